// Round 13
// baseline (346.978 us; speedup 1.0000x reference)
//
#include <hip/hip_runtime.h>
#include <math.h>

#define NB 2
#define HB 8
#define LB 2048
#define EB 64
#define BITSN 32
#define CLN 128
#define ITERS 10
#define TOPKN 32
#define NEGV -10000000.0f
#define NCH 4                 // attn query-chunks per cluster (64 queries each)

typedef unsigned long long u64;
typedef unsigned int u32;

// u16-packed partials: part[nh][j*64 + c/2], fields (c even | c odd << 16),
// j = 0..31 bit-sums, j = 32 counts. All values <= 2048 -> no carry between
// fields under u32 atomicAdd (max field sum 4096 < 65536): exact.
#define PART_NH16 (33 * 64)                     // 2112 dwords per nh
#define PART_ITER16 (NB * HB * PART_NH16)       // 33792 dwords per iteration
#define PART_TOTAL16 (ITERS * PART_ITER16)      // 337920 dwords (~1.35 MB)
#define BITS_BLOCKS 4096                        // NQ/8
#define ZBLOCKS ((PART_TOTAL16 + 255) / 256)

// ---------------------------------------------------------------------------
// Kernel 1: LSH bits (blocks < BITS_BLOCKS) + zeroing of packed partials.
// ---------------------------------------------------------------------------
__global__ __launch_bounds__(256) void bits_zero_kernel(const float* __restrict__ q,
                                                        const float* __restrict__ planes,
                                                        u32* __restrict__ bits,
                                                        u32* __restrict__ zbuf) {
    int tid = threadIdx.x;
    int bid = blockIdx.x;
    if (bid >= BITS_BLOCKS) {
        int i = (bid - BITS_BLOCKS) * 256 + tid;
        if (i < PART_TOTAL16) zbuf[i] = 0u;
        return;
    }
    int wave = tid >> 6;
    int lane = tid & 63;
    int b = lane & 31;
    int which = lane >> 5;
    int qi = bid * 8 + wave * 2 + which;   // qi = (n*H + h)*L + l
    int l = qi & (LB - 1);
    int nh = qi / LB;
    int h = nh & (HB - 1);
    int n = nh / HB;
    const float* qrow = q + (((long long)n * LB + l) * HB + h) * EB;
    const float* prow = planes + b * (EB + 1);
    double acc = (double)prow[EB];                 // bias (the ones column)
    #pragma unroll 8
    for (int e = 0; e < EB; ++e) acc += (double)qrow[e] * (double)prow[e];
    unsigned long long m = __ballot(acc > 0.0);
    if (b == 0) {
        bits[qi] = (u32)(which ? (m >> 32) : (m & 0xffffffffULL));
    }
}

// ---------------------------------------------------------------------------
// K-means iteration: 128 blocks (16 nh x 8 tiles of 256 points), 256 thr.
// u16-packed partials; packed-key argmin (== first-min); per-set-bit LDS
// histogram of OWN 256 points; packed atomic dump (exact, deterministic).
// ---------------------------------------------------------------------------
__global__ __launch_bounds__(256) void kmeans_iter_kernel(const u32* __restrict__ bits,
                                                          const u32* __restrict__ part_prev,
                                                          u32* __restrict__ part_cur,
                                                          const u32* __restrict__ cent_prev_g,
                                                          u32* __restrict__ cent_cur_g,
                                                          int it) {
    __shared__ u32 cent[CLN];
    __shared__ int hist[33 * 128];       // unpacked [j*128+c]
    int tid = threadIdx.x;
    int bid = blockIdx.x;
    int nh = bid >> 3;
    int tile = bid & 7;
    int lane = tid & 63;

    for (int i = tid; i < 33 * 128; i += 256) hist[i] = 0;
    if (tid < CLN) {
        u32 cv;
        if (it == 0) {
            cv = bits[nh * LB + tid * (LB / CLN)];        // init_idx = 16c
        } else {
            const u32* pp = part_prev + nh * PART_NH16;
            int sh = (tid & 1) * 16;
            int cnt = (int)((pp[32 * 64 + (tid >> 1)] >> sh) & 0xffffu);
            u32 nb = 0u;
            #pragma unroll
            for (int j = 0; j < BITSN; ++j) {
                int s = (int)((pp[j * 64 + (tid >> 1)] >> sh) & 0xffffu);
                if (2 * s >= cnt) nb |= (1u << j);
            }
            cv = (cnt > 0) ? nb : cent_prev_g[nh * CLN + tid];
        }
        cent[tid] = cv;
        if (tile == 0) cent_cur_g[nh * CLN + tid] = cv;   // materialize chain
    }
    __syncthreads();

    int l = tile * 256 + tid;
    u32 bv = bits[nh * LB + l];

    // ---- argmin via packed key (d<<7)|c : min == first-min tie rule
    u32 clo = cent[lane], chi = cent[lane + 64];
    u32 best = 0x7fffffffu;
    #pragma unroll 16
    for (int c = 0; c < 64; ++c) {
        u32 cc = (u32)__builtin_amdgcn_readlane((int)clo, c);
        u32 key = ((u32)__popc(bv ^ cc) << 7) | (u32)c;
        best = (key < best) ? key : best;
    }
    #pragma unroll 16
    for (int c = 0; c < 64; ++c) {
        u32 cc = (u32)__builtin_amdgcn_readlane((int)chi, c);
        u32 key = ((u32)__popc(bv ^ cc) << 7) | (u32)(64 + c);
        best = (key < best) ? key : best;
    }
    int bc = (int)(best & 127u);

    // ---- per-set-bit LDS histogram (exact integer adds)
    atomicAdd(&hist[32 * 128 + bc], 1);
    u32 bb = bv;
    while (bb) { int j = __ffs(bb) - 1; atomicAdd(&hist[j * 128 + bc], 1); bb &= bb - 1; }
    __syncthreads();

    // ---- u16-packed dump (pair c=2p, 2p+1); skip zero pairs
    u32* pc = part_cur + nh * PART_NH16;
    for (int i = tid; i < PART_NH16; i += 256) {
        int j = i >> 6, p = i & 63;
        u32 v = (u32)hist[j * 128 + 2 * p] | ((u32)hist[j * 128 + 2 * p + 1] << 16);
        if (v) atomicAdd(&pc[i], v);
    }
}

// ---------------------------------------------------------------------------
// Kernel 3: final assignment + lists + Qg fused, 16 blocks x 1024 thr.
// ---------------------------------------------------------------------------
__global__ __launch_bounds__(1024) void list_qg_final_kernel(const u32* __restrict__ bits,
                                                             const u32* __restrict__ part_prev,
                                                             const u32* __restrict__ cent_prev_g,
                                                             const float* __restrict__ q,
                                                             int* __restrict__ cnt_g,
                                                             int* __restrict__ ofs_g,
                                                             int* __restrict__ list_g,
                                                             float* __restrict__ qgf) {
    __shared__ u32 cent[CLN];
    __shared__ int cnt[CLN];
    __shared__ int cntw[2][16][CLN];       // (group, wave, cluster)
    __shared__ int ofs[CLN];
    __shared__ unsigned short lists[LB];
    int nh = blockIdx.x;
    int tid = threadIdx.x;
    int w = tid >> 6, lane = tid & 63;

    if (tid < CLN) {
        const u32* pp = part_prev + nh * PART_NH16;
        int sh = (tid & 1) * 16;
        int cn = (int)((pp[32 * 64 + (tid >> 1)] >> sh) & 0xffffu);
        u32 nb = 0u;
        #pragma unroll
        for (int j = 0; j < BITSN; ++j) {
            int s = (int)((pp[j * 64 + (tid >> 1)] >> sh) & 0xffffu);
            if (2 * s >= cn) nb |= (1u << j);
        }
        cent[tid] = (cn > 0) ? nb : cent_prev_g[nh * CLN + tid];
        cnt[tid] = 0;
    }
    for (int i = tid; i < 2 * 16 * CLN; i += 1024) (&cntw[0][0][0])[i] = 0;
    __syncthreads();

    int l0 = tid, l1 = tid + 1024;
    u32 bv0 = bits[nh * LB + l0];
    u32 bv1 = bits[nh * LB + l1];
    u32 clo = cent[lane], chi = cent[lane + 64];
    u32 best0 = 0x7fffffffu, best1 = 0x7fffffffu;
    #pragma unroll 16
    for (int c = 0; c < 64; ++c) {
        u32 cc = (u32)__builtin_amdgcn_readlane((int)clo, c);
        u32 k0 = ((u32)__popc(bv0 ^ cc) << 7) | (u32)c;
        u32 k1 = ((u32)__popc(bv1 ^ cc) << 7) | (u32)c;
        best0 = (k0 < best0) ? k0 : best0;
        best1 = (k1 < best1) ? k1 : best1;
    }
    #pragma unroll 16
    for (int c = 0; c < 64; ++c) {
        u32 cc = (u32)__builtin_amdgcn_readlane((int)chi, c);
        u32 k0 = ((u32)__popc(bv0 ^ cc) << 7) | (u32)(64 + c);
        u32 k1 = ((u32)__popc(bv1 ^ cc) << 7) | (u32)(64 + c);
        best0 = (k0 < best0) ? k0 : best0;
        best1 = (k1 < best1) ? k1 : best1;
    }
    int bc0 = (int)(best0 & 127u);
    int bc1 = (int)(best1 & 127u);
    u64 ltmask = (lane == 0) ? 0ULL : (~0ULL >> (64 - lane));

    int rank0 = 0, rank1 = 0;
    for (int c = 0; c < CLN; ++c) {
        u64 m0 = __ballot(bc0 == c);
        u64 m1 = __ballot(bc1 == c);
        if ((m0 | m1) == 0ULL) continue;
        if (bc0 == c) rank0 = (int)__popcll(m0 & ltmask);
        if (bc1 == c) rank1 = (int)__popcll(m1 & ltmask);
        if (lane == 0) {
            int p0 = (int)__popcll(m0), p1 = (int)__popcll(m1);
            if (p0) cntw[0][w][c] = p0;
            if (p1) cntw[1][w][c] = p1;
            atomicAdd(&cnt[c], p0 + p1);
        }
    }
    __syncthreads();
    if (tid == 0) {
        int run = 0;
        for (int c = 0; c < CLN; ++c) { ofs[c] = run; run += cnt[c]; }
    }
    __syncthreads();
    if (tid < CLN) {           // absolute bases per (g,w) in ascending-l order
        int c = tid;
        int run = ofs[c];
        #pragma unroll
        for (int g = 0; g < 2; ++g)
            for (int ww = 0; ww < 16; ++ww) {
                int t = cntw[g][ww][c];
                cntw[g][ww][c] = run;
                run += t;
            }
        cnt_g[nh * CLN + c] = cnt[c];
        ofs_g[nh * CLN + c] = ofs[c];
    }
    __syncthreads();
    {
        int p0 = cntw[0][w][bc0] + rank0;
        int p1 = cntw[1][w][bc1] + rank1;
        lists[p0] = (unsigned short)l0;
        lists[p1] = (unsigned short)l1;
        list_g[nh * LB + p0] = l0;
        list_g[nh * LB + p1] = l1;
    }
    __syncthreads();

    // ---- Qg: wave w handles clusters c = w, w+16, ... (f64 ascending-l)
    int h = nh & (HB - 1);
    int n = nh / HB;
    for (int c = w; c < CLN; c += 16) {
        int cn = cnt[c];
        int o = ofs[c];
        double acc = 0.0;
        for (int i = 0; i < cn; ++i) {
            int l = lists[o + i];
            acc += (double)q[(((long long)n * LB + l) * HB + h) * EB + lane];
        }
        double dcn = (double)(cn > 0 ? cn : 1);
        qgf[(long long)(nh * CLN + c) * EB + lane] = (float)(acc / dcn);
    }
}

// ---------------------------------------------------------------------------
// Kernel 4: scores. Block per (nh, 128-row tile) -> K read exactly once.
// ---------------------------------------------------------------------------
__global__ __launch_bounds__(256) void scores_kernel(const float* __restrict__ kk,
                                                     const float* __restrict__ qgf,
                                                     u32* __restrict__ keys) {
    int bid = blockIdx.x;            // nh*16 + tile
    int nh = bid >> 4;
    int tile = bid & 15;
    int h = nh & (HB - 1);
    int n = nh / HB;
    int w = threadIdx.x >> 6;
    int lane = threadIdx.x & 63;
    int rl = (w & 1) * 64 + lane;    // row within tile
    int l = tile * 128 + rl;
    int cbase = (w >> 1) * 64;       // waves 0,1: c 0-63; waves 2,3: c 64-127

    const float4* kr4 = (const float4*)(kk + (((long long)n * LB + l) * HB + h) * EB);
    float rr[EB];
    #pragma unroll
    for (int i = 0; i < 16; ++i) {
        float4 t4 = kr4[i];
        rr[4 * i] = t4.x; rr[4 * i + 1] = t4.y; rr[4 * i + 2] = t4.z; rr[4 * i + 3] = t4.w;
    }
    const float* qp0 = qgf + ((long long)nh * CLN + cbase) * EB;
    for (int c = 0; c < 64; ++c) {
        const float4* qp = (const float4*)(qp0 + c * EB);   // wave-uniform address
        float acc = 0.f;
        #pragma unroll
        for (int i = 0; i < 16; ++i) {
            float4 qv = qp[i];
            acc = fmaf(qv.x, rr[4 * i], acc);
            acc = fmaf(qv.y, rr[4 * i + 1], acc);
            acc = fmaf(qv.z, rr[4 * i + 2], acc);
            acc = fmaf(qv.w, rr[4 * i + 3], acc);
        }
        u32 u = __float_as_uint(acc);
        u = ((int)u < 0) ? ~u : (u | 0x80000000u);          // monotone f32->u32
        keys[((long long)(nh * CLN + cbase + c)) * LB + l] = u;
    }
}

// ---------------------------------------------------------------------------
// Kernel 5: top-32 per (n,h,c). One wave per block; keys packed
// (key<<32)|(2047-l) -> single u64 compare = (value desc, index asc).
// ---------------------------------------------------------------------------
__global__ __launch_bounds__(64) void topsel_kernel(const u32* __restrict__ keys,
                                                    int* __restrict__ tki_g) {
    int bid = blockIdx.x;            // nh*128 + c
    int lane = threadIdx.x;
    const uint4* kp4 = (const uint4*)(keys + (long long)bid * LB);
    u64 k[32];
    #pragma unroll
    for (int t = 0; t < 8; ++t) {
        uint4 kv = kp4[lane + 64 * t];
        int l0 = (lane + 64 * t) * 4;
        k[4 * t]     = ((u64)kv.x << 32) | (u32)(2047 - l0);
        k[4 * t + 1] = ((u64)kv.y << 32) | (u32)(2047 - (l0 + 1));
        k[4 * t + 2] = ((u64)kv.z << 32) | (u32)(2047 - (l0 + 2));
        k[4 * t + 3] = ((u64)kv.w << 32) | (u32)(2047 - (l0 + 3));
    }
    u64 m0 = k[0], m1 = k[8], m2 = k[16], m3 = k[24];
    #pragma unroll
    for (int t = 1; t < 8; ++t) {
        if (k[t] > m0) m0 = k[t];
        if (k[8 + t] > m1) m1 = k[8 + t];
        if (k[16 + t] > m2) m2 = k[16 + t];
        if (k[24 + t] > m3) m3 = k[24 + t];
    }
    if (m1 > m0) m0 = m1;
    if (m3 > m2) m2 = m3;
    u64 cur = (m2 > m0) ? m2 : m0;

    for (int r = 0; r < TOPKN; ++r) {
        u64 wk = cur;
        #pragma unroll
        for (int off = 1; off < 64; off <<= 1) {
            u64 o = __shfl_xor(wk, off);
            if (o > wk) wk = o;
        }
        if (lane == 0) tki_g[bid * TOPKN + r] = 2047 - (int)(wk & 2047u);
        if (wk == cur) {               // unique owner (indices embedded)
            u64 nm = 0ULL;
            #pragma unroll
            for (int t = 0; t < 32; ++t) {
                u64 kt = k[t];
                u64 cand = (kt < wk) ? kt : 0ULL;
                if (cand > nm) nm = cand;
            }
            cur = nm;
        }
    }
}

// ---------------------------------------------------------------------------
// Kernel 6: attention in 64-query chunks. Block = (nh, c, chunk); exits
// immediately if chunk*64 >= cnt (load-balance: no block handles more than
// 64 queries except the rare >256-member cluster's last chunk). Stages the
// cluster's 32 K rows (65-pad) + 32 V rows once; 4 waves process queries.
// Per-query math identical to the verified R12 kernel.
// ---------------------------------------------------------------------------
__global__ __launch_bounds__(256) void attn_chunk_kernel(const int* __restrict__ tki_g,
                                                         const float* __restrict__ q,
                                                         const float* __restrict__ kk,
                                                         const float* __restrict__ vv,
                                                         const int* __restrict__ cnt_g,
                                                         const int* __restrict__ ofs_g,
                                                         const int* __restrict__ list_g,
                                                         float* __restrict__ out) {
    __shared__ int tki_s[TOPKN];
    __shared__ float ks[TOPKN][EB + 1];   // 65-pad: conflict-free column reads
    __shared__ float vs[TOPKN][EB];
    int bid = blockIdx.x;            // (nh*128 + c)*NCH + chunk
    int chunk = bid & (NCH - 1);
    int cidx = bid >> 2;             // nh*128 + c
    int nh = cidx >> 7;
    int h = nh & (HB - 1);
    int n = nh / HB;
    int tid = threadIdx.x;
    int cnt = cnt_g[cidx];
    int base = chunk * 64;
    if (base >= cnt) return;         // block-uniform early exit
    int endq = (chunk == NCH - 1) ? cnt : ((cnt < base + 64) ? cnt : base + 64);
    int o = ofs_g[cidx];
    int wave = tid >> 6, lane = tid & 63;

    if (tid < TOPKN) tki_s[tid] = tki_g[cidx * TOPKN + tid];
    __syncthreads();

    // ---- stage K_sel / V_sel: thread = (row r, 8-float segment seg)
    {
        int r = tid >> 3, seg = tid & 7;
        int kr = tki_s[r];
        const float* krow = kk + (((long long)n * LB + kr) * HB + h) * EB + seg * 8;
        const float* vrow = vv + (((long long)n * LB + kr) * HB + h) * EB + seg * 8;
        float4 a0 = ((const float4*)krow)[0], a1 = ((const float4*)krow)[1];
        float4 b0 = ((const float4*)vrow)[0], b1 = ((const float4*)vrow)[1];
        int e0 = seg * 8;
        ks[r][e0 + 0] = a0.x; ks[r][e0 + 1] = a0.y; ks[r][e0 + 2] = a0.z; ks[r][e0 + 3] = a0.w;
        ks[r][e0 + 4] = a1.x; ks[r][e0 + 5] = a1.y; ks[r][e0 + 6] = a1.z; ks[r][e0 + 7] = a1.w;
        ((float4*)&vs[r][e0])[0] = b0;
        ((float4*)&vs[r][e0])[1] = b1;
    }
    __syncthreads();

    // ---- per-query attention: wave handles queries i = base+wave, +4, ...
    for (int i = base + wave; i < endq; i += 4) {
        int l = list_g[nh * LB + o + i];
        int j = lane & 31, p = lane >> 5;
        int kidx = tki_s[j];

        const float4* q4 = (const float4*)(q + (((long long)n * LB + l) * HB + h) * EB) + p * 8;
        float part = 0.f;
        #pragma unroll
        for (int i4 = 0; i4 < 8; ++i4) {
            float4 a = q4[i4];
            int e0 = p * 32 + i4 * 4;
            part += a.x * ks[j][e0] + a.y * ks[j][e0 + 1] + a.z * ks[j][e0 + 2] + a.w * ks[j][e0 + 3];
        }
        float qlo = __shfl(part, j);
        float qhi = __shfl(part, j + 32);
        float qk = qlo + qhi;

        bool future = kidx > l;
        float logit = 0.125f * (future ? NEGV : qk);
        float m = logit;
        #pragma unroll
        for (int off = 16; off; off >>= 1) m = fmaxf(m, __shfl_xor(m, off));
        float ex = expf(logit - m);
        float ssum = ex;
        #pragma unroll
        for (int off = 16; off; off >>= 1) ssum += __shfl_xor(ssum, off);
        float a = future ? 0.f : ex / ssum;   // a==0 exactly for masked keys

        float oacc = 0.f;
        #pragma unroll
        for (int jj = 0; jj < TOPKN; ++jj) {
            float aj = __shfl(a, jj);
            oacc = fmaf(aj, vs[jj][lane], oacc);
        }
        out[(((long long)n * LB + l) * HB + h) * EB + lane] = oacc;
    }
}

// ---------------------------------------------------------------------------
extern "C" void kernel_launch(void* const* d_in, const int* in_sizes, int n_in,
                              void* d_out, int out_size, void* d_ws, size_t ws_size,
                              hipStream_t stream) {
    const float* q = (const float*)d_in[0];
    const float* k = (const float*)d_in[1];
    const float* v = (const float*)d_in[2];
    const float* planes = (const float*)d_in[3];
    float* out = (float*)d_out;

    char* ws = (char*)d_ws;
    u32* bits     = (u32*)(ws);                    // 128 KB
    int* cnt_g    = (int*)(ws + 0x40000);          // 8 KB
    int* ofs_g    = (int*)(ws + 0x42000);          // 8 KB
    int* list_g   = (int*)(ws + 0x44000);          // 128 KB
    float* qgf    = (float*)(ws + 0x64000);        // 512 KB
    int* tki_g    = (int*)(ws + 0xE4000);          // 256 KB (2048 x 32 ints)
    u32* keys     = (u32*)(ws + 0x124000);         // 16 MB
    // clustering scratch ALIASES the keys region (dead once scores runs):
    u32* part_all = (u32*)(ws + 0x124000);         // 1.35 MB packed partials
    u32* cents0   = (u32*)(ws + 0x124000 + 0x180000);
    u32* cents1   = (u32*)(ws + 0x124000 + 0x182000);

    bits_zero_kernel<<<BITS_BLOCKS + ZBLOCKS, 256, 0, stream>>>(q, planes, bits, part_all);

    for (int it = 0; it < ITERS; ++it) {
        const u32* pp = part_all + (it == 0 ? 0 : (it - 1)) * PART_ITER16;
        u32* pc       = part_all + it * PART_ITER16;
        const u32* cprev = (it & 1) ? cents0 : cents1;   // cent_{it-1}
        u32* ccur        = (it & 1) ? cents1 : cents0;   // cent_it
        kmeans_iter_kernel<<<NB * HB * 8, 256, 0, stream>>>(bits, pp, pc, cprev, ccur, it);
    }
    // cent_10 from part[9] (carry cent_9, parity 1), + lists + Qg
    list_qg_final_kernel<<<NB * HB, 1024, 0, stream>>>(
        bits, part_all + 9 * PART_ITER16, cents1, q, cnt_g, ofs_g, list_g, qgf);
    scores_kernel<<<NB * HB * 16, 256, 0, stream>>>(k, qgf, keys);
    topsel_kernel<<<NB * HB * CLN, 64, 0, stream>>>(keys, tki_g);
    attn_chunk_kernel<<<NB * HB * CLN * NCH, 256, 0, stream>>>(tki_g, q, k, v,
                                                               cnt_g, ofs_g, list_g, out);
}

// Round 14
// 301.136 us; speedup vs baseline: 1.1522x; 1.1522x over previous
//
#include <hip/hip_runtime.h>
#include <math.h>

#define NB 2
#define HB 8
#define LB 2048
#define EB 64
#define BITSN 32
#define CLN 128
#define ITERS 10
#define TOPKN 32
#define NEGV -10000000.0f

typedef unsigned long long u64;
typedef unsigned int u32;

// u16-packed partials: part[nh][j*64 + c/2], fields (c even | c odd << 16),
// j = 0..31 bit-sums, j = 32 counts. All values <= 2048 -> no carry between
// fields under u32 atomicAdd (max field sum 4096 < 65536): exact.
#define PART_NH16 (33 * 64)                     // 2112 dwords per nh
#define PART_ITER16 (NB * HB * PART_NH16)       // 33792 dwords per iteration
#define PART_TOTAL16 (ITERS * PART_ITER16)      // 337920 dwords (~1.35 MB)
#define BITS_BLOCKS 4096                        // NQ/8
#define ZBLOCKS ((PART_TOTAL16 + 255) / 256)

// ---------------------------------------------------------------------------
// Kernel 1: LSH bits (blocks < BITS_BLOCKS) + zeroing of packed partials.
// ---------------------------------------------------------------------------
__global__ __launch_bounds__(256) void bits_zero_kernel(const float* __restrict__ q,
                                                        const float* __restrict__ planes,
                                                        u32* __restrict__ bits,
                                                        u32* __restrict__ zbuf) {
    int tid = threadIdx.x;
    int bid = blockIdx.x;
    if (bid >= BITS_BLOCKS) {
        int i = (bid - BITS_BLOCKS) * 256 + tid;
        if (i < PART_TOTAL16) zbuf[i] = 0u;
        return;
    }
    int wave = tid >> 6;
    int lane = tid & 63;
    int b = lane & 31;
    int which = lane >> 5;
    int qi = bid * 8 + wave * 2 + which;   // qi = (n*H + h)*L + l
    int l = qi & (LB - 1);
    int nh = qi / LB;
    int h = nh & (HB - 1);
    int n = nh / HB;
    const float* qrow = q + (((long long)n * LB + l) * HB + h) * EB;
    const float* prow = planes + b * (EB + 1);
    double acc = (double)prow[EB];                 // bias (the ones column)
    #pragma unroll 8
    for (int e = 0; e < EB; ++e) acc += (double)qrow[e] * (double)prow[e];
    unsigned long long m = __ballot(acc > 0.0);
    if (b == 0) {
        bits[qi] = (u32)(which ? (m >> 32) : (m & 0xffffffffULL));
    }
}

// ---------------------------------------------------------------------------
// K-means iteration: 128 blocks (16 nh x 8 tiles of 256 points), 256 thr.
// u16-packed partials; packed-key argmin (== first-min); per-set-bit LDS
// histogram of OWN 256 points; packed atomic dump (exact, deterministic).
// ---------------------------------------------------------------------------
__global__ __launch_bounds__(256) void kmeans_iter_kernel(const u32* __restrict__ bits,
                                                          const u32* __restrict__ part_prev,
                                                          u32* __restrict__ part_cur,
                                                          const u32* __restrict__ cent_prev_g,
                                                          u32* __restrict__ cent_cur_g,
                                                          int it) {
    __shared__ u32 cent[CLN];
    __shared__ int hist[33 * 128];       // unpacked [j*128+c]
    int tid = threadIdx.x;
    int bid = blockIdx.x;
    int nh = bid >> 3;
    int tile = bid & 7;
    int lane = tid & 63;

    for (int i = tid; i < 33 * 128; i += 256) hist[i] = 0;
    if (tid < CLN) {
        u32 cv;
        if (it == 0) {
            cv = bits[nh * LB + tid * (LB / CLN)];        // init_idx = 16c
        } else {
            const u32* pp = part_prev + nh * PART_NH16;
            int sh = (tid & 1) * 16;
            int cnt = (int)((pp[32 * 64 + (tid >> 1)] >> sh) & 0xffffu);
            u32 nb = 0u;
            #pragma unroll
            for (int j = 0; j < BITSN; ++j) {
                int s = (int)((pp[j * 64 + (tid >> 1)] >> sh) & 0xffffu);
                if (2 * s >= cnt) nb |= (1u << j);
            }
            cv = (cnt > 0) ? nb : cent_prev_g[nh * CLN + tid];
        }
        cent[tid] = cv;
        if (tile == 0) cent_cur_g[nh * CLN + tid] = cv;   // materialize chain
    }
    __syncthreads();

    int l = tile * 256 + tid;
    u32 bv = bits[nh * LB + l];

    // ---- argmin via packed key (d<<7)|c : min == first-min tie rule
    u32 clo = cent[lane], chi = cent[lane + 64];
    u32 best = 0x7fffffffu;
    #pragma unroll 16
    for (int c = 0; c < 64; ++c) {
        u32 cc = (u32)__builtin_amdgcn_readlane((int)clo, c);
        u32 key = ((u32)__popc(bv ^ cc) << 7) | (u32)c;
        best = (key < best) ? key : best;
    }
    #pragma unroll 16
    for (int c = 0; c < 64; ++c) {
        u32 cc = (u32)__builtin_amdgcn_readlane((int)chi, c);
        u32 key = ((u32)__popc(bv ^ cc) << 7) | (u32)(64 + c);
        best = (key < best) ? key : best;
    }
    int bc = (int)(best & 127u);

    // ---- per-set-bit LDS histogram (exact integer adds)
    atomicAdd(&hist[32 * 128 + bc], 1);
    u32 bb = bv;
    while (bb) { int j = __ffs(bb) - 1; atomicAdd(&hist[j * 128 + bc], 1); bb &= bb - 1; }
    __syncthreads();

    // ---- u16-packed dump (pair c=2p, 2p+1); skip zero pairs
    u32* pc = part_cur + nh * PART_NH16;
    for (int i = tid; i < PART_NH16; i += 256) {
        int j = i >> 6, p = i & 63;
        u32 v = (u32)hist[j * 128 + 2 * p] | ((u32)hist[j * 128 + 2 * p + 1] << 16);
        if (v) atomicAdd(&pc[i], v);
    }
}

// ---------------------------------------------------------------------------
// Kernel 3: final assignment + lists + Qg fused, 16 blocks x 1024 thr.
// cent_10 from packed part[9] (carry cent_9), argmin 2 pts/thread (also
// written to assign_g for the gather-attn kernel), ballot-rank ascending-l
// member lists, f64 ascending-l Qg means.
// ---------------------------------------------------------------------------
__global__ __launch_bounds__(1024) void list_qg_final_kernel(const u32* __restrict__ bits,
                                                             const u32* __restrict__ part_prev,
                                                             const u32* __restrict__ cent_prev_g,
                                                             const float* __restrict__ q,
                                                             int* __restrict__ assign_g,
                                                             int* __restrict__ cnt_g,
                                                             int* __restrict__ ofs_g,
                                                             int* __restrict__ list_g,
                                                             float* __restrict__ qgf) {
    __shared__ u32 cent[CLN];
    __shared__ int cnt[CLN];
    __shared__ int cntw[2][16][CLN];       // (group, wave, cluster)
    __shared__ int ofs[CLN];
    __shared__ unsigned short lists[LB];
    int nh = blockIdx.x;
    int tid = threadIdx.x;
    int w = tid >> 6, lane = tid & 63;

    if (tid < CLN) {
        const u32* pp = part_prev + nh * PART_NH16;
        int sh = (tid & 1) * 16;
        int cn = (int)((pp[32 * 64 + (tid >> 1)] >> sh) & 0xffffu);
        u32 nb = 0u;
        #pragma unroll
        for (int j = 0; j < BITSN; ++j) {
            int s = (int)((pp[j * 64 + (tid >> 1)] >> sh) & 0xffffu);
            if (2 * s >= cn) nb |= (1u << j);
        }
        cent[tid] = (cn > 0) ? nb : cent_prev_g[nh * CLN + tid];
        cnt[tid] = 0;
    }
    for (int i = tid; i < 2 * 16 * CLN; i += 1024) (&cntw[0][0][0])[i] = 0;
    __syncthreads();

    int l0 = tid, l1 = tid + 1024;
    u32 bv0 = bits[nh * LB + l0];
    u32 bv1 = bits[nh * LB + l1];
    u32 clo = cent[lane], chi = cent[lane + 64];
    u32 best0 = 0x7fffffffu, best1 = 0x7fffffffu;
    #pragma unroll 16
    for (int c = 0; c < 64; ++c) {
        u32 cc = (u32)__builtin_amdgcn_readlane((int)clo, c);
        u32 k0 = ((u32)__popc(bv0 ^ cc) << 7) | (u32)c;
        u32 k1 = ((u32)__popc(bv1 ^ cc) << 7) | (u32)c;
        best0 = (k0 < best0) ? k0 : best0;
        best1 = (k1 < best1) ? k1 : best1;
    }
    #pragma unroll 16
    for (int c = 0; c < 64; ++c) {
        u32 cc = (u32)__builtin_amdgcn_readlane((int)chi, c);
        u32 k0 = ((u32)__popc(bv0 ^ cc) << 7) | (u32)(64 + c);
        u32 k1 = ((u32)__popc(bv1 ^ cc) << 7) | (u32)(64 + c);
        best0 = (k0 < best0) ? k0 : best0;
        best1 = (k1 < best1) ? k1 : best1;
    }
    int bc0 = (int)(best0 & 127u);
    int bc1 = (int)(best1 & 127u);
    assign_g[nh * LB + l0] = bc0;
    assign_g[nh * LB + l1] = bc1;
    u64 ltmask = (lane == 0) ? 0ULL : (~0ULL >> (64 - lane));

    int rank0 = 0, rank1 = 0;
    for (int c = 0; c < CLN; ++c) {
        u64 m0 = __ballot(bc0 == c);
        u64 m1 = __ballot(bc1 == c);
        if ((m0 | m1) == 0ULL) continue;
        if (bc0 == c) rank0 = (int)__popcll(m0 & ltmask);
        if (bc1 == c) rank1 = (int)__popcll(m1 & ltmask);
        if (lane == 0) {
            int p0 = (int)__popcll(m0), p1 = (int)__popcll(m1);
            if (p0) cntw[0][w][c] = p0;
            if (p1) cntw[1][w][c] = p1;
            atomicAdd(&cnt[c], p0 + p1);
        }
    }
    __syncthreads();
    if (tid == 0) {
        int run = 0;
        for (int c = 0; c < CLN; ++c) { ofs[c] = run; run += cnt[c]; }
    }
    __syncthreads();
    if (tid < CLN) {           // absolute bases per (g,w) in ascending-l order
        int c = tid;
        int run = ofs[c];
        #pragma unroll
        for (int g = 0; g < 2; ++g)
            for (int ww = 0; ww < 16; ++ww) {
                int t = cntw[g][ww][c];
                cntw[g][ww][c] = run;
                run += t;
            }
        cnt_g[nh * CLN + c] = cnt[c];
        ofs_g[nh * CLN + c] = ofs[c];
    }
    __syncthreads();
    {
        int p0 = cntw[0][w][bc0] + rank0;
        int p1 = cntw[1][w][bc1] + rank1;
        lists[p0] = (unsigned short)l0;
        lists[p1] = (unsigned short)l1;
        list_g[nh * LB + p0] = l0;
        list_g[nh * LB + p1] = l1;
    }
    __syncthreads();

    // ---- Qg: wave w handles clusters c = w, w+16, ... (f64 ascending-l)
    int h = nh & (HB - 1);
    int n = nh / HB;
    for (int c = w; c < CLN; c += 16) {
        int cn = cnt[c];
        int o = ofs[c];
        double acc = 0.0;
        for (int i = 0; i < cn; ++i) {
            int l = lists[o + i];
            acc += (double)q[(((long long)n * LB + l) * HB + h) * EB + lane];
        }
        double dcn = (double)(cn > 0 ? cn : 1);
        qgf[(long long)(nh * CLN + c) * EB + lane] = (float)(acc / dcn);
    }
}

// ---------------------------------------------------------------------------
// Kernel 4: scores. Block per (nh, 128-row tile) -> K read exactly once.
// ---------------------------------------------------------------------------
__global__ __launch_bounds__(256) void scores_kernel(const float* __restrict__ kk,
                                                     const float* __restrict__ qgf,
                                                     u32* __restrict__ keys) {
    int bid = blockIdx.x;            // nh*16 + tile
    int nh = bid >> 4;
    int tile = bid & 15;
    int h = nh & (HB - 1);
    int n = nh / HB;
    int w = threadIdx.x >> 6;
    int lane = threadIdx.x & 63;
    int rl = (w & 1) * 64 + lane;    // row within tile
    int l = tile * 128 + rl;
    int cbase = (w >> 1) * 64;       // waves 0,1: c 0-63; waves 2,3: c 64-127

    const float4* kr4 = (const float4*)(kk + (((long long)n * LB + l) * HB + h) * EB);
    float rr[EB];
    #pragma unroll
    for (int i = 0; i < 16; ++i) {
        float4 t4 = kr4[i];
        rr[4 * i] = t4.x; rr[4 * i + 1] = t4.y; rr[4 * i + 2] = t4.z; rr[4 * i + 3] = t4.w;
    }
    const float* qp0 = qgf + ((long long)nh * CLN + cbase) * EB;
    for (int c = 0; c < 64; ++c) {
        const float4* qp = (const float4*)(qp0 + c * EB);   // wave-uniform address
        float acc = 0.f;
        #pragma unroll
        for (int i = 0; i < 16; ++i) {
            float4 qv = qp[i];
            acc = fmaf(qv.x, rr[4 * i], acc);
            acc = fmaf(qv.y, rr[4 * i + 1], acc);
            acc = fmaf(qv.z, rr[4 * i + 2], acc);
            acc = fmaf(qv.w, rr[4 * i + 3], acc);
        }
        u32 u = __float_as_uint(acc);
        u = ((int)u < 0) ? ~u : (u | 0x80000000u);          // monotone f32->u32
        keys[((long long)(nh * CLN + cbase + c)) * LB + l] = u;
    }
}

// ---------------------------------------------------------------------------
// Kernel 5: top-32 per (n,h,c). One wave per block; keys packed
// (key<<32)|(2047-l) -> single u64 compare = (value desc, index asc).
// ---------------------------------------------------------------------------
__global__ __launch_bounds__(64) void topsel_kernel(const u32* __restrict__ keys,
                                                    int* __restrict__ tki_g) {
    int bid = blockIdx.x;            // nh*128 + c
    int lane = threadIdx.x;
    const uint4* kp4 = (const uint4*)(keys + (long long)bid * LB);
    u64 k[32];
    #pragma unroll
    for (int t = 0; t < 8; ++t) {
        uint4 kv = kp4[lane + 64 * t];
        int l0 = (lane + 64 * t) * 4;
        k[4 * t]     = ((u64)kv.x << 32) | (u32)(2047 - l0);
        k[4 * t + 1] = ((u64)kv.y << 32) | (u32)(2047 - (l0 + 1));
        k[4 * t + 2] = ((u64)kv.z << 32) | (u32)(2047 - (l0 + 2));
        k[4 * t + 3] = ((u64)kv.w << 32) | (u32)(2047 - (l0 + 3));
    }
    u64 m0 = k[0], m1 = k[8], m2 = k[16], m3 = k[24];
    #pragma unroll
    for (int t = 1; t < 8; ++t) {
        if (k[t] > m0) m0 = k[t];
        if (k[8 + t] > m1) m1 = k[8 + t];
        if (k[16 + t] > m2) m2 = k[16 + t];
        if (k[24 + t] > m3) m3 = k[24 + t];
    }
    if (m1 > m0) m0 = m1;
    if (m3 > m2) m2 = m3;
    u64 cur = (m2 > m0) ? m2 : m0;

    for (int r = 0; r < TOPKN; ++r) {
        u64 wk = cur;
        #pragma unroll
        for (int off = 1; off < 64; off <<= 1) {
            u64 o = __shfl_xor(wk, off);
            if (o > wk) wk = o;
        }
        if (lane == 0) tki_g[bid * TOPKN + r] = 2047 - (int)(wk & 2047u);
        if (wk == cur) {               // unique owner (indices embedded)
            u64 nm = 0ULL;
            #pragma unroll
            for (int t = 0; t < 32; ++t) {
                u64 kt = k[t];
                u64 cand = (kt < wk) ? kt : 0ULL;
                if (cand > nm) nm = cand;
            }
            cur = nm;
        }
    }
}

// ---------------------------------------------------------------------------
// Kernel 6: gather attention (R7-verified form). One wave per query; the 32
// V columns are preloaded into registers before the QK/softmax dependency
// chain (32 independent coalesced 256B-row loads in flight).
// ---------------------------------------------------------------------------
__global__ __launch_bounds__(256) void attn_kernel(const float* __restrict__ q,
                                                   const float* __restrict__ kk,
                                                   const float* __restrict__ vv,
                                                   const int* __restrict__ assign_g,
                                                   const int* __restrict__ tki_g,
                                                   float* __restrict__ out) {
    int tid = threadIdx.x;
    int wave = tid >> 6, lane = tid & 63;
    int qi = blockIdx.x * 4 + wave;   // (nh)*L + l
    int l = qi & (LB - 1);
    int nh = qi / LB;
    int h = nh & (HB - 1);
    int n = nh / HB;
    int c = assign_g[qi];
    const int* krow = tki_g + (nh * CLN + c) * TOPKN;
    int j = lane & 31, p = lane >> 5;
    int kidx = krow[j];

    // preload V: vreg[jj] = V[kj(jj)][lane]  (coalesced 256B rows, high ILP)
    const float* vbase = vv + ((long long)n * LB * HB + h) * EB;  // + ki*H*E + e
    float vreg[TOPKN];
    #pragma unroll
    for (int jj = 0; jj < TOPKN; ++jj) {
        int kj = __shfl(kidx, jj);
        vreg[jj] = vbase[(long long)kj * (HB * EB) + lane];
    }

    const float4* q4 = (const float4*)(q + (((long long)n * LB + l) * HB + h) * EB) + p * 8;
    const float4* k4 = (const float4*)(kk + (((long long)n * LB + kidx) * HB + h) * EB) + p * 8;
    float part = 0.f;
    #pragma unroll
    for (int i = 0; i < 8; ++i) {
        float4 a = q4[i], b = k4[i];
        part += a.x * b.x + a.y * b.y + a.z * b.z + a.w * b.w;
    }
    float qlo = __shfl(part, j);
    float qhi = __shfl(part, j + 32);
    float qk = qlo + qhi;

    bool future = kidx > l;
    float logit = 0.125f * (future ? NEGV : qk);
    float m = logit;
    #pragma unroll
    for (int off = 16; off; off >>= 1) m = fmaxf(m, __shfl_xor(m, off));
    float ex = expf(logit - m);
    float ssum = ex;
    #pragma unroll
    for (int off = 16; off; off >>= 1) ssum += __shfl_xor(ssum, off);
    float a = future ? 0.f : ex / ssum;   // a==0 exactly for masked keys

    float oacc = 0.f;
    #pragma unroll
    for (int jj = 0; jj < TOPKN; ++jj) {
        float aj = __shfl(a, jj);
        oacc = fmaf(aj, vreg[jj], oacc);  // aj==0 contributes exactly 0
    }
    out[(((long long)n * LB + l) * HB + h) * EB + lane] = oacc;
}

// ---------------------------------------------------------------------------
extern "C" void kernel_launch(void* const* d_in, const int* in_sizes, int n_in,
                              void* d_out, int out_size, void* d_ws, size_t ws_size,
                              hipStream_t stream) {
    const float* q = (const float*)d_in[0];
    const float* k = (const float*)d_in[1];
    const float* v = (const float*)d_in[2];
    const float* planes = (const float*)d_in[3];
    float* out = (float*)d_out;

    const int NQ = NB * HB * LB;                  // 32768
    char* ws = (char*)d_ws;
    u32* bits     = (u32*)(ws);                    // 128 KB
    int* assign_g = (int*)(ws + 0x20000);          // 128 KB
    int* cnt_g    = (int*)(ws + 0x40000);          // 8 KB
    int* ofs_g    = (int*)(ws + 0x42000);          // 8 KB
    int* list_g   = (int*)(ws + 0x44000);          // 128 KB
    float* qgf    = (float*)(ws + 0x64000);        // 512 KB
    int* tki_g    = (int*)(ws + 0xE4000);          // 256 KB (2048 x 32 ints)
    u32* keys     = (u32*)(ws + 0x124000);         // 16 MB
    // clustering scratch ALIASES the keys region (dead once scores runs):
    u32* part_all = (u32*)(ws + 0x124000);         // 1.35 MB packed partials
    u32* cents0   = (u32*)(ws + 0x124000 + 0x180000);
    u32* cents1   = (u32*)(ws + 0x124000 + 0x182000);

    bits_zero_kernel<<<BITS_BLOCKS + ZBLOCKS, 256, 0, stream>>>(q, planes, bits, part_all);

    for (int it = 0; it < ITERS; ++it) {
        const u32* pp = part_all + (it == 0 ? 0 : (it - 1)) * PART_ITER16;
        u32* pc       = part_all + it * PART_ITER16;
        const u32* cprev = (it & 1) ? cents0 : cents1;   // cent_{it-1}
        u32* ccur        = (it & 1) ? cents1 : cents0;   // cent_it
        kmeans_iter_kernel<<<NB * HB * 8, 256, 0, stream>>>(bits, pp, pc, cprev, ccur, it);
    }
    // cent_10 from part[9] (carry cent_9, parity 1) + assign + lists + Qg
    list_qg_final_kernel<<<NB * HB, 1024, 0, stream>>>(
        bits, part_all + 9 * PART_ITER16, cents1, q, assign_g, cnt_g, ofs_g, list_g, qgf);
    scores_kernel<<<NB * HB * 16, 256, 0, stream>>>(k, qgf, keys);
    topsel_kernel<<<NB * HB * CLN, 64, 0, stream>>>(keys, tki_g);
    attn_kernel<<<NQ / 4, 256, 0, stream>>>(q, k, v, assign_g, tki_g, out);
}

// Round 15
// 289.017 us; speedup vs baseline: 1.2005x; 1.0419x over previous
//
#include <hip/hip_runtime.h>
#include <math.h>

#define NB 2
#define HB 8
#define LB 2048
#define EB 64
#define BITSN 32
#define CLN 128
#define ITERS 10
#define TOPKN 32
#define NEGV -10000000.0f

typedef unsigned long long u64;
typedef unsigned int u32;

// u16-packed partials: part[nh][j*64 + c/2], fields (c even | c odd << 16),
// j = 0..31 bit-sums, j = 32 counts. All values <= 2048 -> no carry between
// fields under u32 atomicAdd (max field sum 4096 < 65536): exact.
#define PART_NH16 (33 * 64)                     // 2112 dwords per nh
#define PART_ITER16 (NB * HB * PART_NH16)       // 33792 dwords per iteration
#define PART_TOTAL16 (ITERS * PART_ITER16)      // 337920 dwords (~1.35 MB)
#define BITS_BLOCKS 4096                        // NQ/8
#define ZBLOCKS ((PART_TOTAL16 + 255) / 256)

// ---------------------------------------------------------------------------
// Kernel 1: LSH bits (blocks < BITS_BLOCKS) + zeroing of packed partials.
// ---------------------------------------------------------------------------
__global__ __launch_bounds__(256) void bits_zero_kernel(const float* __restrict__ q,
                                                        const float* __restrict__ planes,
                                                        u32* __restrict__ bits,
                                                        u32* __restrict__ zbuf) {
    int tid = threadIdx.x;
    int bid = blockIdx.x;
    if (bid >= BITS_BLOCKS) {
        int i = (bid - BITS_BLOCKS) * 256 + tid;
        if (i < PART_TOTAL16) zbuf[i] = 0u;
        return;
    }
    int wave = tid >> 6;
    int lane = tid & 63;
    int b = lane & 31;
    int which = lane >> 5;
    int qi = bid * 8 + wave * 2 + which;   // qi = (n*H + h)*L + l
    int l = qi & (LB - 1);
    int nh = qi / LB;
    int h = nh & (HB - 1);
    int n = nh / HB;
    const float* qrow = q + (((long long)n * LB + l) * HB + h) * EB;
    const float* prow = planes + b * (EB + 1);
    double acc = (double)prow[EB];                 // bias (the ones column)
    #pragma unroll 8
    for (int e = 0; e < EB; ++e) acc += (double)qrow[e] * (double)prow[e];
    unsigned long long m = __ballot(acc > 0.0);
    if (b == 0) {
        bits[qi] = (u32)(which ? (m >> 32) : (m & 0xffffffffULL));
    }
}

// ---------------------------------------------------------------------------
// K-means iteration: 128 blocks (16 nh x 8 tiles of 256 points), 256 thr.
// u16-packed partials; packed-key argmin (== first-min); per-set-bit LDS
// histogram of OWN 256 points; packed atomic dump (exact, deterministic).
// ---------------------------------------------------------------------------
__global__ __launch_bounds__(256) void kmeans_iter_kernel(const u32* __restrict__ bits,
                                                          const u32* __restrict__ part_prev,
                                                          u32* __restrict__ part_cur,
                                                          const u32* __restrict__ cent_prev_g,
                                                          u32* __restrict__ cent_cur_g,
                                                          int it) {
    __shared__ u32 cent[CLN];
    __shared__ int hist[33 * 128];       // unpacked [j*128+c]
    int tid = threadIdx.x;
    int bid = blockIdx.x;
    int nh = bid >> 3;
    int tile = bid & 7;
    int lane = tid & 63;

    for (int i = tid; i < 33 * 128; i += 256) hist[i] = 0;
    if (tid < CLN) {
        u32 cv;
        if (it == 0) {
            cv = bits[nh * LB + tid * (LB / CLN)];        // init_idx = 16c
        } else {
            const u32* pp = part_prev + nh * PART_NH16;
            int sh = (tid & 1) * 16;
            int cnt = (int)((pp[32 * 64 + (tid >> 1)] >> sh) & 0xffffu);
            u32 nb = 0u;
            #pragma unroll
            for (int j = 0; j < BITSN; ++j) {
                int s = (int)((pp[j * 64 + (tid >> 1)] >> sh) & 0xffffu);
                if (2 * s >= cnt) nb |= (1u << j);
            }
            cv = (cnt > 0) ? nb : cent_prev_g[nh * CLN + tid];
        }
        cent[tid] = cv;
        if (tile == 0) cent_cur_g[nh * CLN + tid] = cv;   // materialize chain
    }
    __syncthreads();

    int l = tile * 256 + tid;
    u32 bv = bits[nh * LB + l];

    // ---- argmin via packed key (d<<7)|c : min == first-min tie rule
    u32 clo = cent[lane], chi = cent[lane + 64];
    u32 best = 0x7fffffffu;
    #pragma unroll 16
    for (int c = 0; c < 64; ++c) {
        u32 cc = (u32)__builtin_amdgcn_readlane((int)clo, c);
        u32 key = ((u32)__popc(bv ^ cc) << 7) | (u32)c;
        best = (key < best) ? key : best;
    }
    #pragma unroll 16
    for (int c = 0; c < 64; ++c) {
        u32 cc = (u32)__builtin_amdgcn_readlane((int)chi, c);
        u32 key = ((u32)__popc(bv ^ cc) << 7) | (u32)(64 + c);
        best = (key < best) ? key : best;
    }
    int bc = (int)(best & 127u);

    // ---- per-set-bit LDS histogram (exact integer adds)
    atomicAdd(&hist[32 * 128 + bc], 1);
    u32 bb = bv;
    while (bb) { int j = __ffs(bb) - 1; atomicAdd(&hist[j * 128 + bc], 1); bb &= bb - 1; }
    __syncthreads();

    // ---- u16-packed dump (pair c=2p, 2p+1); skip zero pairs
    u32* pc = part_cur + nh * PART_NH16;
    for (int i = tid; i < PART_NH16; i += 256) {
        int j = i >> 6, p = i & 63;
        u32 v = (u32)hist[j * 128 + 2 * p] | ((u32)hist[j * 128 + 2 * p + 1] << 16);
        if (v) atomicAdd(&pc[i], v);
    }
}

// ---------------------------------------------------------------------------
// Kernel 3: final assignment + lists + Qg fused, 16 blocks x 1024 thr.
// cent_10 from packed part[9] (carry cent_9), argmin 2 pts/thread, then
// ballot-rank ascending-l member lists (+ per-position cluster ids csort_g),
// f64 ascending-l Qg means.
// ---------------------------------------------------------------------------
__global__ __launch_bounds__(1024) void list_qg_final_kernel(const u32* __restrict__ bits,
                                                             const u32* __restrict__ part_prev,
                                                             const u32* __restrict__ cent_prev_g,
                                                             const float* __restrict__ q,
                                                             int* __restrict__ csort_g,
                                                             int* __restrict__ cnt_g,
                                                             int* __restrict__ ofs_g,
                                                             int* __restrict__ list_g,
                                                             float* __restrict__ qgf) {
    __shared__ u32 cent[CLN];
    __shared__ int cnt[CLN];
    __shared__ int cntw[2][16][CLN];       // (group, wave, cluster)
    __shared__ int ofs[CLN];
    __shared__ unsigned short lists[LB];
    int nh = blockIdx.x;
    int tid = threadIdx.x;
    int w = tid >> 6, lane = tid & 63;

    if (tid < CLN) {
        const u32* pp = part_prev + nh * PART_NH16;
        int sh = (tid & 1) * 16;
        int cn = (int)((pp[32 * 64 + (tid >> 1)] >> sh) & 0xffffu);
        u32 nb = 0u;
        #pragma unroll
        for (int j = 0; j < BITSN; ++j) {
            int s = (int)((pp[j * 64 + (tid >> 1)] >> sh) & 0xffffu);
            if (2 * s >= cn) nb |= (1u << j);
        }
        cent[tid] = (cn > 0) ? nb : cent_prev_g[nh * CLN + tid];
        cnt[tid] = 0;
    }
    for (int i = tid; i < 2 * 16 * CLN; i += 1024) (&cntw[0][0][0])[i] = 0;
    __syncthreads();

    int l0 = tid, l1 = tid + 1024;
    u32 bv0 = bits[nh * LB + l0];
    u32 bv1 = bits[nh * LB + l1];
    u32 clo = cent[lane], chi = cent[lane + 64];
    u32 best0 = 0x7fffffffu, best1 = 0x7fffffffu;
    #pragma unroll 16
    for (int c = 0; c < 64; ++c) {
        u32 cc = (u32)__builtin_amdgcn_readlane((int)clo, c);
        u32 k0 = ((u32)__popc(bv0 ^ cc) << 7) | (u32)c;
        u32 k1 = ((u32)__popc(bv1 ^ cc) << 7) | (u32)c;
        best0 = (k0 < best0) ? k0 : best0;
        best1 = (k1 < best1) ? k1 : best1;
    }
    #pragma unroll 16
    for (int c = 0; c < 64; ++c) {
        u32 cc = (u32)__builtin_amdgcn_readlane((int)chi, c);
        u32 k0 = ((u32)__popc(bv0 ^ cc) << 7) | (u32)(64 + c);
        u32 k1 = ((u32)__popc(bv1 ^ cc) << 7) | (u32)(64 + c);
        best0 = (k0 < best0) ? k0 : best0;
        best1 = (k1 < best1) ? k1 : best1;
    }
    int bc0 = (int)(best0 & 127u);
    int bc1 = (int)(best1 & 127u);
    u64 ltmask = (lane == 0) ? 0ULL : (~0ULL >> (64 - lane));

    int rank0 = 0, rank1 = 0;
    for (int c = 0; c < CLN; ++c) {
        u64 m0 = __ballot(bc0 == c);
        u64 m1 = __ballot(bc1 == c);
        if ((m0 | m1) == 0ULL) continue;
        if (bc0 == c) rank0 = (int)__popcll(m0 & ltmask);
        if (bc1 == c) rank1 = (int)__popcll(m1 & ltmask);
        if (lane == 0) {
            int p0 = (int)__popcll(m0), p1 = (int)__popcll(m1);
            if (p0) cntw[0][w][c] = p0;
            if (p1) cntw[1][w][c] = p1;
            atomicAdd(&cnt[c], p0 + p1);
        }
    }
    __syncthreads();
    if (tid == 0) {
        int run = 0;
        for (int c = 0; c < CLN; ++c) { ofs[c] = run; run += cnt[c]; }
    }
    __syncthreads();
    if (tid < CLN) {           // absolute bases per (g,w) in ascending-l order
        int c = tid;
        int run = ofs[c];
        #pragma unroll
        for (int g = 0; g < 2; ++g)
            for (int ww = 0; ww < 16; ++ww) {
                int t = cntw[g][ww][c];
                cntw[g][ww][c] = run;
                run += t;
            }
        cnt_g[nh * CLN + c] = cnt[c];
        ofs_g[nh * CLN + c] = ofs[c];
    }
    __syncthreads();
    {
        int p0 = cntw[0][w][bc0] + rank0;
        int p1 = cntw[1][w][bc1] + rank1;
        lists[p0] = (unsigned short)l0;
        lists[p1] = (unsigned short)l1;
        list_g[nh * LB + p0] = l0;
        list_g[nh * LB + p1] = l1;
        csort_g[nh * LB + p0] = bc0;        // cluster id at list position
        csort_g[nh * LB + p1] = bc1;
    }
    __syncthreads();

    // ---- Qg: wave w handles clusters c = w, w+16, ... (f64 ascending-l)
    int h = nh & (HB - 1);
    int n = nh / HB;
    for (int c = w; c < CLN; c += 16) {
        int cn = cnt[c];
        int o = ofs[c];
        double acc = 0.0;
        for (int i = 0; i < cn; ++i) {
            int l = lists[o + i];
            acc += (double)q[(((long long)n * LB + l) * HB + h) * EB + lane];
        }
        double dcn = (double)(cn > 0 ? cn : 1);
        qgf[(long long)(nh * CLN + c) * EB + lane] = (float)(acc / dcn);
    }
}

// ---------------------------------------------------------------------------
// Kernel 4: scores. Block per (nh, 128-row tile) -> K read exactly once.
// ---------------------------------------------------------------------------
__global__ __launch_bounds__(256) void scores_kernel(const float* __restrict__ kk,
                                                     const float* __restrict__ qgf,
                                                     u32* __restrict__ keys) {
    int bid = blockIdx.x;            // nh*16 + tile
    int nh = bid >> 4;
    int tile = bid & 15;
    int h = nh & (HB - 1);
    int n = nh / HB;
    int w = threadIdx.x >> 6;
    int lane = threadIdx.x & 63;
    int rl = (w & 1) * 64 + lane;    // row within tile
    int l = tile * 128 + rl;
    int cbase = (w >> 1) * 64;       // waves 0,1: c 0-63; waves 2,3: c 64-127

    const float4* kr4 = (const float4*)(kk + (((long long)n * LB + l) * HB + h) * EB);
    float rr[EB];
    #pragma unroll
    for (int i = 0; i < 16; ++i) {
        float4 t4 = kr4[i];
        rr[4 * i] = t4.x; rr[4 * i + 1] = t4.y; rr[4 * i + 2] = t4.z; rr[4 * i + 3] = t4.w;
    }
    const float* qp0 = qgf + ((long long)nh * CLN + cbase) * EB;
    for (int c = 0; c < 64; ++c) {
        const float4* qp = (const float4*)(qp0 + c * EB);   // wave-uniform address
        float acc = 0.f;
        #pragma unroll
        for (int i = 0; i < 16; ++i) {
            float4 qv = qp[i];
            acc = fmaf(qv.x, rr[4 * i], acc);
            acc = fmaf(qv.y, rr[4 * i + 1], acc);
            acc = fmaf(qv.z, rr[4 * i + 2], acc);
            acc = fmaf(qv.w, rr[4 * i + 3], acc);
        }
        u32 u = __float_as_uint(acc);
        u = ((int)u < 0) ? ~u : (u | 0x80000000u);          // monotone f32->u32
        keys[((long long)(nh * CLN + cbase + c)) * LB + l] = u;
    }
}

// ---------------------------------------------------------------------------
// Kernel 5: top-32 per (n,h,c). One wave per block; keys packed
// (key<<32)|(2047-l) -> single u64 compare = (value desc, index asc).
// ---------------------------------------------------------------------------
__global__ __launch_bounds__(64) void topsel_kernel(const u32* __restrict__ keys,
                                                    int* __restrict__ tki_g) {
    int bid = blockIdx.x;            // nh*128 + c
    int lane = threadIdx.x;
    const uint4* kp4 = (const uint4*)(keys + (long long)bid * LB);
    u64 k[32];
    #pragma unroll
    for (int t = 0; t < 8; ++t) {
        uint4 kv = kp4[lane + 64 * t];
        int l0 = (lane + 64 * t) * 4;
        k[4 * t]     = ((u64)kv.x << 32) | (u32)(2047 - l0);
        k[4 * t + 1] = ((u64)kv.y << 32) | (u32)(2047 - (l0 + 1));
        k[4 * t + 2] = ((u64)kv.z << 32) | (u32)(2047 - (l0 + 2));
        k[4 * t + 3] = ((u64)kv.w << 32) | (u32)(2047 - (l0 + 3));
    }
    u64 m0 = k[0], m1 = k[8], m2 = k[16], m3 = k[24];
    #pragma unroll
    for (int t = 1; t < 8; ++t) {
        if (k[t] > m0) m0 = k[t];
        if (k[8 + t] > m1) m1 = k[8 + t];
        if (k[16 + t] > m2) m2 = k[16 + t];
        if (k[24 + t] > m3) m3 = k[24 + t];
    }
    if (m1 > m0) m0 = m1;
    if (m3 > m2) m2 = m3;
    u64 cur = (m2 > m0) ? m2 : m0;

    for (int r = 0; r < TOPKN; ++r) {
        u64 wk = cur;
        #pragma unroll
        for (int off = 1; off < 64; off <<= 1) {
            u64 o = __shfl_xor(wk, off);
            if (o > wk) wk = o;
        }
        if (lane == 0) tki_g[bid * TOPKN + r] = 2047 - (int)(wk & 2047u);
        if (wk == cur) {               // unique owner (indices embedded)
            u64 nm = 0ULL;
            #pragma unroll
            for (int t = 0; t < 32; ++t) {
                u64 kt = k[t];
                u64 cand = (kt < wk) ? kt : 0ULL;
                if (cand > nm) nm = cand;
            }
            cur = nm;
        }
    }
}

// ---------------------------------------------------------------------------
// Kernel 6: gather attention in CLUSTER-SORTED order. One wave per list
// position: runs of same-cluster waves share the tki row and the 32 K/V
// rows -> dependent gathers hit L1/hot-L2 instead of cold L2/HBM.
// Per-query math identical to the verified R14 kernel.
// ---------------------------------------------------------------------------
__global__ __launch_bounds__(256) void attn_kernel(const float* __restrict__ q,
                                                   const float* __restrict__ kk,
                                                   const float* __restrict__ vv,
                                                   const int* __restrict__ list_g,
                                                   const int* __restrict__ csort_g,
                                                   const int* __restrict__ tki_g,
                                                   float* __restrict__ out) {
    int tid = threadIdx.x;
    int wave = tid >> 6, lane = tid & 63;
    int idx = blockIdx.x * 4 + wave;  // list position: nh*L + pos
    int nh = idx >> 11;               // LB = 2048
    int pos = idx & (LB - 1);
    int l = list_g[nh * LB + pos];
    int c = csort_g[nh * LB + pos];
    int h = nh & (HB - 1);
    int n = nh / HB;
    const int* krow = tki_g + (nh * CLN + c) * TOPKN;
    int j = lane & 31, p = lane >> 5;
    int kidx = krow[j];

    // preload V: vreg[jj] = V[kj(jj)][lane]  (coalesced 256B rows, high ILP)
    const float* vbase = vv + ((long long)n * LB * HB + h) * EB;  // + ki*H*E + e
    float vreg[TOPKN];
    #pragma unroll
    for (int jj = 0; jj < TOPKN; ++jj) {
        int kj = __shfl(kidx, jj);
        vreg[jj] = vbase[(long long)kj * (HB * EB) + lane];
    }

    const float4* q4 = (const float4*)(q + (((long long)n * LB + l) * HB + h) * EB) + p * 8;
    const float4* k4 = (const float4*)(kk + (((long long)n * LB + kidx) * HB + h) * EB) + p * 8;
    float part = 0.f;
    #pragma unroll
    for (int i = 0; i < 8; ++i) {
        float4 a = q4[i], b = k4[i];
        part += a.x * b.x + a.y * b.y + a.z * b.z + a.w * b.w;
    }
    float qlo = __shfl(part, j);
    float qhi = __shfl(part, j + 32);
    float qk = qlo + qhi;

    bool future = kidx > l;
    float logit = 0.125f * (future ? NEGV : qk);
    float m = logit;
    #pragma unroll
    for (int off = 16; off; off >>= 1) m = fmaxf(m, __shfl_xor(m, off));
    float ex = expf(logit - m);
    float ssum = ex;
    #pragma unroll
    for (int off = 16; off; off >>= 1) ssum += __shfl_xor(ssum, off);
    float a = future ? 0.f : ex / ssum;   // a==0 exactly for masked keys

    float oacc = 0.f;
    #pragma unroll
    for (int jj = 0; jj < TOPKN; ++jj) {
        float aj = __shfl(a, jj);
        oacc = fmaf(aj, vreg[jj], oacc);  // aj==0 contributes exactly 0
    }
    out[(((long long)n * LB + l) * HB + h) * EB + lane] = oacc;
}

// ---------------------------------------------------------------------------
extern "C" void kernel_launch(void* const* d_in, const int* in_sizes, int n_in,
                              void* d_out, int out_size, void* d_ws, size_t ws_size,
                              hipStream_t stream) {
    const float* q = (const float*)d_in[0];
    const float* k = (const float*)d_in[1];
    const float* v = (const float*)d_in[2];
    const float* planes = (const float*)d_in[3];
    float* out = (float*)d_out;

    const int NQ = NB * HB * LB;                  // 32768
    char* ws = (char*)d_ws;
    u32* bits     = (u32*)(ws);                    // 128 KB
    int* csort_g  = (int*)(ws + 0x20000);          // 128 KB (cluster per position)
    int* cnt_g    = (int*)(ws + 0x40000);          // 8 KB
    int* ofs_g    = (int*)(ws + 0x42000);          // 8 KB
    int* list_g   = (int*)(ws + 0x44000);          // 128 KB
    float* qgf    = (float*)(ws + 0x64000);        // 512 KB
    int* tki_g    = (int*)(ws + 0xE4000);          // 256 KB (2048 x 32 ints)
    u32* keys     = (u32*)(ws + 0x124000);         // 16 MB
    // clustering scratch ALIASES the keys region (dead once scores runs):
    u32* part_all = (u32*)(ws + 0x124000);         // 1.35 MB packed partials
    u32* cents0   = (u32*)(ws + 0x124000 + 0x180000);
    u32* cents1   = (u32*)(ws + 0x124000 + 0x182000);

    bits_zero_kernel<<<BITS_BLOCKS + ZBLOCKS, 256, 0, stream>>>(q, planes, bits, part_all);

    for (int it = 0; it < ITERS; ++it) {
        const u32* pp = part_all + (it == 0 ? 0 : (it - 1)) * PART_ITER16;
        u32* pc       = part_all + it * PART_ITER16;
        const u32* cprev = (it & 1) ? cents0 : cents1;   // cent_{it-1}
        u32* ccur        = (it & 1) ? cents1 : cents0;   // cent_it
        kmeans_iter_kernel<<<NB * HB * 8, 256, 0, stream>>>(bits, pp, pc, cprev, ccur, it);
    }
    // cent_10 from part[9] (carry cent_9, parity 1) + csort + lists + Qg
    list_qg_final_kernel<<<NB * HB, 1024, 0, stream>>>(
        bits, part_all + 9 * PART_ITER16, cents1, q, csort_g, cnt_g, ofs_g, list_g, qgf);
    scores_kernel<<<NB * HB * 16, 256, 0, stream>>>(k, qgf, keys);
    topsel_kernel<<<NB * HB * CLN, 64, 0, stream>>>(keys, tki_g);
    attn_kernel<<<NQ / 4, 256, 0, stream>>>(q, k, v, list_g, csort_g, tki_g, out);
}